// Round 7
// baseline (375.229 us; speedup 1.0000x reference)
//
#include <hip/hip_runtime.h>

// ---------------------------------------------------------------------------
// VoxMLP round 7: R6 main kernel (unchanged) + XCD-affine prep.
//   prep: [blocks 0..263] weights -> fp8 MFMA fragments (wo pre-scaled 2^13,
//         feature-K permutation). [blocks 264..16647] bf16x4 [v,gx,gy,gz]
//         data grid, 4 voxels/thread, slab-swizzled: (bid-264)&7 picks a
//         32-plane i-slab (-> one XCD under bid%8 round-robin), k-fastest
//         order within slab so x/y/z halo reuse stays in that XCD's L2.
//   voxmlp: 4 independent waves x 32 points. Lanes 0..31: 8x8B dgrid gather
//     +trilinear (out0/out1 + LDS stash). Lanes 32..63: pos-enc features ->
//     fp8 -> LDS. MLP via v_mfma_f32_16x16x32_fp8_fp8 (A=weights[unit],
//     B=activations[k][point], C=[unit][point]); epilogue scales by 2^-13.
//   LDS: bufH row 136 B (34 dw = 2 mod 32 -> 2-way, free), fbuf row 88 B.
//   28672 B/block -> 5 blocks/CU.
// ---------------------------------------------------------------------------

typedef __attribute__((ext_vector_type(4))) float f4;
typedef long long llg;   // 8 x fp8 = 2 VGPRs

__device__ __forceinline__ float bf2f(unsigned int u) {
    union { float f; unsigned int i; } v; v.i = u << 16; return v.f;
}
__device__ __forceinline__ unsigned short f2bf(float f) {
    union { float f; unsigned int i; } v; v.f = f;
    unsigned int x = v.i;
    return (unsigned short)((x + 0x7fffu + ((x >> 16) & 1u)) >> 16);
}
__device__ __forceinline__ unsigned int pkbf(float a, float b) {
    unsigned int r;
    asm("v_cvt_pk_bf16_f32 %0, %1, %2" : "=v"(r) : "v"(a), "v"(b));
    return r;
}
__device__ __forceinline__ float gv(const float* __restrict__ g, int i, int j, int k) {
    return g[(i * 256 + j) * 256 + k];
}
// feature permutation: slot k' -> original feature index (or -1 = zero pad)
__device__ __forceinline__ int featmap(int kp) {
    if (kp < 3) return kp;
    if (kp == 3) return -1;
    const int m = kp - 4, b = m / 6, r = m - 6 * b, d = r >> 1, c = r & 1;
    return 3 + 6 * b + 3 * c + d;
}

// ---- d_ws layout ----
// bytes [0, 67584): fp8 weight fragments: L0@0(K64), L1@8192(K128),
//   L2@24576, L3@40960(K192), out@65536(K128,NT1, wo*2^13)
// shorts from 131072 (byte 262144): bf16x4 data grid (16.7M voxels * 8 B)
#define WS_TOTAL 67584
#define SWZ_BLOCKS 264          // 264*256 == 67584; 264 = 8*33 keeps XCD phase
#define DG_BLOCKS 16384         // 8 slabs x 2048 blocks, 4 voxels/thread
#define DG_OFF_SH 131072
#define WS_NEED (262144ull + 16777216ull * 8ull)
#define WO_SCALE 8192.0f
#define WO_INV   (1.0f / 8192.0f)

__global__ __launch_bounds__(256) void prep(
    const float* __restrict__ g,
    const float* __restrict__ w0, const float* __restrict__ w1,
    const float* __restrict__ w2, const float* __restrict__ w3,
    const float* __restrict__ wo,
    unsigned char* __restrict__ ws8, unsigned short* __restrict__ dg,
    int do_dgrid)
{
    const int bid = blockIdx.x;
    if (bid < SWZ_BLOCKS) {
        // ---------------- weight swizzle -> fp8 ----------------
        int idx = bid * 256 + threadIdx.x;
        const float* src; int base, NT, Kact, Nact, ld;
        if (idx < 8192)       { src = w0; base = 0;     NT = 8; Kact = 64;  Nact = 128; ld = 128; }
        else if (idx < 24576) { src = w1; base = 8192;  NT = 8; Kact = 128; Nact = 128; ld = 128; }
        else if (idx < 40960) { src = w2; base = 24576; NT = 8; Kact = 128; Nact = 128; ld = 128; }
        else if (idx < 65536) { src = w3; base = 40960; NT = 8; Kact = 192; Nact = 128; ld = 128; }
        else                  { src = wo; base = 65536; NT = 1; Kact = 128; Nact = 3;   ld = 3;   }
        int local = idx - base;
        int j = local & 7;
        int lane = (local >> 3) & 63;
        int chunk = local >> 9;              // = kt*NT + nt
        int nt = chunk % NT, kt = chunk / NT;
        int k = kt * 32 + ((lane >> 4) << 3) + j;   // k = kt*32 + quad*8 + j
        int n = nt * 16 + (lane & 15);              // unit = nt*16 + (lane&15)
        float v = 0.0f;
        if (k < Kact && n < Nact) {
            int ko = k;
            if (base == 0)            ko = featmap(k);
            else if (base == 40960 && k >= 128) {
                int f = featmap(k - 128);
                ko = (f < 0) ? -1 : 128 + f;
            }
            if (ko >= 0) v = src[ko * ld + n];
            if (base == 65536) v *= WO_SCALE;        // keep wo out of fp8 underflow
        }
        int p = __builtin_amdgcn_cvt_pk_fp8_f32(v, v, 0, false);
        ws8[idx] = (unsigned char)(p & 0xff);
    } else if (do_dgrid) {
        // -------- data grid build, XCD-affine (4 voxels/thread) --------
        const int bd   = bid - SWZ_BLOCKS;          // [0, 16384)
        const int slab = bd & 7;                    // -> XCD slab under bid%8
        const int w    = bd >> 3;                   // [0, 2048) within slab
        const int L    = w * 256 + threadIdx.x;     // [0, 524288)
        const int kc   = L & 63;                    // k-chunk (4 voxels)
        const int j    = (L >> 6) & 255;
        const int il   = L >> 14;                   // [0, 32)
        const int i    = slab * 32 + il;
        const int k0   = kc << 2;

        const float* row = g + (i * 256 + j) * 256;
        const f4 self = *(const f4*)(row + k0);
        const f4 xp = *(const f4*)(g + (min(i + 1, 255) * 256 + j) * 256 + k0);
        const f4 xm = *(const f4*)(g + (max(i - 1, 0)   * 256 + j) * 256 + k0);
        const f4 yp = *(const f4*)(g + (i * 256 + min(j + 1, 255)) * 256 + k0);
        const f4 ym = *(const f4*)(g + (i * 256 + max(j - 1, 0))   * 256 + k0);
        const float zlo = row[max(k0 - 1, 0)];
        const float zhi = row[min(k0 + 4, 255)];
        float zv[6] = {zlo, self[0], self[1], self[2], self[3], zhi};
        unsigned int o[8];
        #pragma unroll
        for (int q = 0; q < 4; ++q) {
            o[q * 2 + 0] = pkbf(self[q], (xp[q] - xm[q]) * 63.75f);
            o[q * 2 + 1] = pkbf((yp[q] - ym[q]) * 63.75f, (zv[q + 2] - zv[q]) * 63.75f);
        }
        unsigned short* dst = dg + (size_t)(((i * 256 + j) * 256 + k0)) * 4;
        *(uint4*)(dst)     = *(const uint4*)(o);
        *(uint4*)(dst + 8) = *(const uint4*)(o + 4);
    }
}

// per-wave LDS (bytes): bufH 32 rows x 136 B (units 0..127 + pad),
// fbuf 32 rows x 88 B: [0..63] fp8 features, [64..75] 3 fp32 c1..c3 stash.
#define HSTRIDE_B 136
#define FSTRIDE_B 88
#define WV_BYTES (32 * HSTRIDE_B + 32 * FSTRIDE_B)   // 7168

template<bool FAST>
__global__ __launch_bounds__(256, 5) void voxmlp(
    const float* __restrict__ x, const float* __restrict__ grid,
    const unsigned char* __restrict__ ws8, const unsigned short* __restrict__ dg,
    const float* __restrict__ b0, const float* __restrict__ b1,
    const float* __restrict__ b2, const float* __restrict__ b3,
    const float* __restrict__ bo,
    float* __restrict__ out, int B)
{
    __shared__ unsigned char smem[WV_BYTES * 4];   // 28672 B -> 5 blocks/CU

    const int lane = threadIdx.x & 63;
    const int wave = threadIdx.x >> 6;
    const int quad = lane >> 4;
    const int lm   = lane & 15;
    unsigned char* bufH = smem + wave * WV_BYTES;
    unsigned char* fbuf = bufH + 32 * HSTRIDE_B;

    const int pbase = blockIdx.x * 128 + wave * 32;

    // ================= Phase 1 ============================================
    const int p2   = lane & 31;
    const int role = lane >> 5;
    const int pid  = pbase + p2;

    const float px = x[pid * 3 + 0];
    const float py = x[pid * 3 + 1];
    const float pz = x[pid * 3 + 2];

    if (role == 0) {
        const float fx = (px + 1.0f) * 127.5f;
        const float fy = (py + 1.0f) * 127.5f;
        const float fz = (pz + 1.0f) * 127.5f;
        const float fx0 = floorf(fx), fy0 = floorf(fy), fz0 = floorf(fz);
        const float xd = fx - fx0, yd = fy - fy0, zd = fz - fz0;
        const int ix0 = min(max((int)fx0, 0), 255);
        const int iy0 = min(max((int)fy0, 0), 255);
        const int iz0 = min(max((int)fz0, 0), 255);
        const int ix1 = min(ix0 + 1, 255);
        const int iy1 = min(iy0 + 1, 255);
        const int iz1 = min(iz0 + 1, 255);

        float ret0 = 0.f, c1 = 0.f, c2 = 0.f, c3 = 0.f;
        if (FAST) {
            #pragma unroll
            for (int c = 0; c < 8; ++c) {
                const int i = (c & 4) ? ix1 : ix0;
                const int j = (c & 2) ? iy1 : iy0;
                const int k = (c & 1) ? iz1 : iz0;
                const float wgt = ((c & 4) ? xd : 1.0f - xd) *
                                  ((c & 2) ? yd : 1.0f - yd) *
                                  ((c & 1) ? zd : 1.0f - zd);
                const uint2 w = *(const uint2*)(dg + (size_t)((i * 256 + j) * 256 + k) * 4);
                ret0 = fmaf(wgt, bf2f(w.x & 0xffffu), ret0);
                c1   = fmaf(wgt, bf2f(w.x >> 16),     c1);
                c2   = fmaf(wgt, bf2f(w.y & 0xffffu), c2);
                c3   = fmaf(wgt, bf2f(w.y >> 16),     c3);
            }
        } else {
            #pragma unroll
            for (int c = 0; c < 8; ++c) {
                const int i = (c & 4) ? ix1 : ix0;
                const int j = (c & 2) ? iy1 : iy0;
                const int k = (c & 1) ? iz1 : iz0;
                const float wgt = ((c & 4) ? xd : 1.0f - xd) *
                                  ((c & 2) ? yd : 1.0f - yd) *
                                  ((c & 1) ? zd : 1.0f - zd);
                const float v  = gv(grid, i, j, k);
                const float gx = (gv(grid, min(i + 1, 255), j, k) - gv(grid, max(i - 1, 0), j, k)) * 63.75f;
                const float gy = (gv(grid, i, min(j + 1, 255), k) - gv(grid, i, max(j - 1, 0), k)) * 63.75f;
                const float gz = (gv(grid, i, j, min(k + 1, 255)) - gv(grid, i, j, max(k - 1, 0))) * 63.75f;
                ret0 = fmaf(wgt, v,  ret0);
                c1   = fmaf(wgt, gx, c1);
                c2   = fmaf(wgt, gy, c2);
                c3   = fmaf(wgt, gz, c3);
            }
        }
        out[pid] = ret0;
        out[B + pid * 3 + 0] = c1;
        out[B + pid * 3 + 1] = c2;
        out[B + pid * 3 + 2] = c3;
        float* cst = (float*)(fbuf + p2 * FSTRIDE_B + 64);
        cst[0] = c1; cst[1] = c2; cst[2] = c3;
    } else {
        // 63 features in permuted slot order, fp8-packed -> 8x ds_write_b64
        float s[64];
        s[0] = px; s[1] = py; s[2] = pz; s[3] = 0.0f;
        const float crd[3] = {px, py, pz};
        float sc = 1.0f;
        #pragma unroll
        for (int b = 0; b < 10; ++b) {
            #pragma unroll
            for (int d = 0; d < 3; ++d) {
                float sv, cv;
                __sincosf(crd[d] * sc, &sv, &cv);
                s[4 + b * 6 + d * 2 + 0] = sv;
                s[4 + b * 6 + d * 2 + 1] = cv;
            }
            sc *= 2.0f;
        }
        unsigned int dw[16];
        #pragma unroll
        for (int i = 0; i < 16; ++i) {
            int d = __builtin_amdgcn_cvt_pk_fp8_f32(s[4 * i + 0], s[4 * i + 1], 0, false);
            d     = __builtin_amdgcn_cvt_pk_fp8_f32(s[4 * i + 2], s[4 * i + 3], d, true);
            dw[i] = (unsigned int)d;
        }
        unsigned char* fb = fbuf + p2 * FSTRIDE_B;
        #pragma unroll
        for (int i = 0; i < 8; ++i) {
            uint2 pk; pk.x = dw[2 * i]; pk.y = dw[2 * i + 1];
            *(uint2*)(fb + i * 8) = pk;
        }
    }
    __builtin_amdgcn_s_barrier();   // phase-align waves (L1 weight reuse)

    // ================= MLP via fp8 MFMA ====================================
    llg af[2][6];
    const int arow0 = lm * HSTRIDE_B + quad * 8;
    const int frow0 = lm * FSTRIDE_B + quad * 8;

    auto store_tile = [&](f4 acc, int pt, int ut) {
        int d = __builtin_amdgcn_cvt_pk_fp8_f32(fmaxf(acc[0], 0.f), fmaxf(acc[1], 0.f), 0, false);
        d     = __builtin_amdgcn_cvt_pk_fp8_f32(fmaxf(acc[2], 0.f), fmaxf(acc[3], 0.f), d, true);
        *(int*)(bufH + (pt * 16 + lm) * HSTRIDE_B + ut * 16 + quad * 4) = d;
    };

    // ---- L0: fbuf(K=64) -> bufH ----
    #pragma unroll
    for (int pt = 0; pt < 2; ++pt)
        #pragma unroll
        for (int kt = 0; kt < 2; ++kt)
            af[pt][kt] = *(const llg*)(fbuf + pt * 16 * FSTRIDE_B + frow0 + kt * 32);
    #pragma unroll
    for (int ut = 0; ut < 8; ++ut) {
        llg wf[2];
        #pragma unroll
        for (int kt = 0; kt < 2; ++kt)
            wf[kt] = *(const llg*)(ws8 + 0 + (((kt * 8 + ut) * 64 + lane) << 3));
        const f4 bias = *(const f4*)(b0 + ut * 16 + quad * 4);
        #pragma unroll
        for (int pt = 0; pt < 2; ++pt) {
            f4 acc = bias;
            #pragma unroll
            for (int kt = 0; kt < 2; ++kt)
                acc = __builtin_amdgcn_mfma_f32_16x16x32_fp8_fp8(wf[kt], af[pt][kt], acc, 0, 0, 0);
            store_tile(acc, pt, ut);
        }
    }
    __builtin_amdgcn_s_barrier();

    // ---- L1, L2: bufH(K=128) -> bufH ----
    #pragma unroll
    for (int layer = 0; layer < 2; ++layer) {
        const unsigned char* wsl = ws8 + (layer == 0 ? 8192 : 24576);
        const float* bias_p = (layer == 0) ? b1 : b2;
        #pragma unroll
        for (int pt = 0; pt < 2; ++pt)
            #pragma unroll
            for (int kt = 0; kt < 4; ++kt)
                af[pt][kt] = *(const llg*)(bufH + pt * 16 * HSTRIDE_B + arow0 + kt * 32);
        #pragma unroll
        for (int ut = 0; ut < 8; ++ut) {
            llg wf[4];
            #pragma unroll
            for (int kt = 0; kt < 4; ++kt)
                wf[kt] = *(const llg*)(wsl + (((kt * 8 + ut) * 64 + lane) << 3));
            const f4 bias = *(const f4*)(bias_p + ut * 16 + quad * 4);
            #pragma unroll
            for (int pt = 0; pt < 2; ++pt) {
                f4 acc = bias;
                #pragma unroll
                for (int kt = 0; kt < 4; ++kt)
                    acc = __builtin_amdgcn_mfma_f32_16x16x32_fp8_fp8(wf[kt], af[pt][kt], acc, 0, 0, 0);
                store_tile(acc, pt, ut);
            }
        }
        __builtin_amdgcn_s_barrier();
    }

    // ---- L3: concat(bufH 128, fbuf 64) K=192 -> bufH ----
    #pragma unroll
    for (int pt = 0; pt < 2; ++pt) {
        #pragma unroll
        for (int kt = 0; kt < 4; ++kt)
            af[pt][kt] = *(const llg*)(bufH + pt * 16 * HSTRIDE_B + arow0 + kt * 32);
        #pragma unroll
        for (int kk = 0; kk < 2; ++kk)
            af[pt][4 + kk] = *(const llg*)(fbuf + pt * 16 * FSTRIDE_B + frow0 + kk * 32);
    }
    #pragma unroll
    for (int ut = 0; ut < 8; ++ut) {
        llg wf[6];
        #pragma unroll
        for (int kt = 0; kt < 6; ++kt)
            wf[kt] = *(const llg*)(ws8 + 40960 + (((kt * 8 + ut) * 64 + lane) << 3));
        const f4 bias = *(const f4*)(b3 + ut * 16 + quad * 4);
        #pragma unroll
        for (int pt = 0; pt < 2; ++pt) {
            f4 acc = bias;
            #pragma unroll
            for (int kt = 0; kt < 6; ++kt)
                acc = __builtin_amdgcn_mfma_f32_16x16x32_fp8_fp8(wf[kt], af[pt][kt], acc, 0, 0, 0);
            store_tile(acc, pt, ut);
        }
    }
    __builtin_amdgcn_s_barrier();

    // ---- output layer (K=128, N=3, wo scaled 2^13) + Rodrigues epilogue ----
    #pragma unroll
    for (int pt = 0; pt < 2; ++pt)
        #pragma unroll
        for (int kt = 0; kt < 4; ++kt)
            af[pt][kt] = *(const llg*)(bufH + pt * 16 * HSTRIDE_B + arow0 + kt * 32);
    llg wf[4];
    #pragma unroll
    for (int kt = 0; kt < 4; ++kt)
        wf[kt] = *(const llg*)(ws8 + 65536 + ((kt * 64 + lane) << 3));

    const float bo0 = bo[0], bo1 = bo[1], bo2 = bo[2];
    #pragma unroll
    for (int pt = 0; pt < 2; ++pt) {
        f4 acc = {0.f, 0.f, 0.f, 0.f};
        #pragma unroll
        for (int kt = 0; kt < 4; ++kt)
            acc = __builtin_amdgcn_mfma_f32_16x16x32_fp8_fp8(wf[kt], af[pt][kt], acc, 0, 0, 0);

        const int pp = pt * 16 + lm;
        const float* cst = (const float*)(fbuf + pp * FSTRIDE_B + 64);
        const float g1 = cst[0], g2 = cst[1], g3 = cst[2];
        const float r0 = acc[0] * WO_INV + bo0;
        const float r1 = acc[1] * WO_INV + bo1;
        const float r2 = acc[2] * WO_INV + bo2;
        const float theta = sqrtf(fmaf(r0, r0, fmaf(r1, r1, r2 * r2)) + 1e-12f);
        const float it = __builtin_amdgcn_rcpf(theta);
        const float e0 = r0 * it, e1 = r1 * it, e2 = r2 * it;
        const float a = sqrtf(fmaf(g1, g1, fmaf(g2, g2, g3 * g3)) + 1e-12f);
        const float ia = __builtin_amdgcn_rcpf(a);
        const float v0 = g1 * ia, v1 = g2 * ia, v2 = g3 * ia;
        float st, ct;
        __sincosf(theta, &st, &ct);
        const float cx = e1 * v2 - e2 * v1;
        const float cy = e2 * v0 - e0 * v2;
        const float cz = e0 * v1 - e1 * v0;
        const float om = (1.0f - ct) * (e0 * v0 + e1 * v1 + e2 * v2);
        if (quad == 0) {
            const int pid2 = pbase + pp;
            out[4 * B + pid2 * 3 + 0] = a * (ct * v0 + st * cx + om * e0);
            out[4 * B + pid2 * 3 + 1] = a * (ct * v1 + st * cy + om * e1);
            out[4 * B + pid2 * 3 + 2] = a * (ct * v2 + st * cz + om * e2);
        }
    }
}

extern "C" void kernel_launch(void* const* d_in, const int* in_sizes, int n_in,
                              void* d_out, int out_size, void* d_ws, size_t ws_size,
                              hipStream_t stream)
{
    const float* x    = (const float*)d_in[0];
    const float* grid = (const float*)d_in[1];
    const float* w0   = (const float*)d_in[2];
    const float* b0   = (const float*)d_in[3];
    const float* w1   = (const float*)d_in[4];
    const float* b1   = (const float*)d_in[5];
    const float* w2   = (const float*)d_in[6];
    const float* b2   = (const float*)d_in[7];
    const float* w3   = (const float*)d_in[8];
    const float* b3   = (const float*)d_in[9];
    const float* wo   = (const float*)d_in[10];
    const float* bo   = (const float*)d_in[11];
    float* out = (float*)d_out;
    unsigned char* ws8 = (unsigned char*)d_ws;
    unsigned short* dg = (unsigned short*)d_ws + DG_OFF_SH;

    const int B = in_sizes[0] / 3;        // 1,048,576
    const int fast = (ws_size >= WS_NEED) ? 1 : 0;
    const int nprep = fast ? (SWZ_BLOCKS + DG_BLOCKS) : SWZ_BLOCKS;
    prep<<<nprep, 256, 0, stream>>>(grid, w0, w1, w2, w3, wo, ws8, dg, fast);
    if (fast)
        voxmlp<true><<<B / 128, 256, 0, stream>>>(x, grid, ws8, dg, b0, b1, b2, b3, bo, out, B);
    else
        voxmlp<false><<<B / 128, 256, 0, stream>>>(x, grid, ws8, dg, b0, b1, b2, b3, bo, out, B);
}